// Round 4
// baseline (1878.229 us; speedup 1.0000x reference)
//
#include <hip/hip_runtime.h>

typedef unsigned short u16;
typedef __attribute__((ext_vector_type(8))) short s8v;   // 8 x bf16
typedef __attribute__((ext_vector_type(4))) float f4v;   // 4 x f32

__device__ __forceinline__ float bf2f(u16 u) {
    union { unsigned u; float f; } c; c.u = ((unsigned)u) << 16; return c.f;
}
__device__ __forceinline__ u16 f2bf(float f) {
    union { float f; unsigned u; } c; c.f = f;
    return (u16)((c.u + 0x7FFFu + ((c.u >> 16) & 1u)) >> 16);
}
__device__ __forceinline__ f4v mfma16(s8v a, s8v b, f4v c) {
    return __builtin_amdgcn_mfma_f32_16x16x32_bf16(a, b, c, 0, 0, 0);
}

__constant__ int POOL_A[12] = {2,5,1,0,8,14,11,10, 0,2,5,4};
__constant__ int POOL_B[12] = {3,6,4,7,9,15,12,13, 1,3,6,7};

// Wfrag[((h*12+nt)*16+kt)*512 + lane*8 + j] = B[n=nt*16+l15][k=kt*32+quad*8+j]
// nt 0-3: Wq head-cols; 4-7: diag(g)Wk; 8-11: diag(g)Wv
__global__ void pack_wcat(const float* __restrict__ Wq, const float* __restrict__ Wkv,
                          const float* __restrict__ gamma, u16* __restrict__ Wfrag) {
    int blk = blockIdx.x;               // 1536 blocks
    int kt = blk & 15, hn = blk >> 4;
    int nt = hn % 12, h = hn / 12;
    int lane = threadIdx.x, l15 = lane & 15, quad = lane >> 4;
    int r0 = kt * 32 + quad * 8;
    s8v v;
    if (nt < 4) {
        int c = h * 64 + nt * 16 + l15;
#pragma unroll
        for (int j = 0; j < 8; ++j) v[j] = (short)f2bf(Wq[(size_t)(r0 + j) * 512 + c]);
    } else {
        int c = (nt < 8) ? (h * 64 + (nt - 4) * 16 + l15)
                         : (512 + h * 64 + (nt - 8) * 16 + l15);
#pragma unroll
        for (int j = 0; j < 8; ++j)
            v[j] = (short)f2bf(gamma[r0 + j] * Wkv[(size_t)(r0 + j) * 1024 + c]);
    }
    *(s8v*)&Wfrag[(size_t)blk * 512 + lane * 8] = v;
}

// Wpfrag[((h*2+kt)*32+n)*512 + lane*8 + j] = Wproj[h*64+kt*32+quad*8+j][n*16+l15]
__global__ void pack_wp(const float* __restrict__ Wproj, u16* __restrict__ Wpfrag) {
    int blk = blockIdx.x;               // 512 blocks
    int n = blk & 31, hk = blk >> 5;
    int kt = hk & 1, h = hk >> 1;
    int lane = threadIdx.x, l15 = lane & 15, quad = lane >> 4;
    int r0 = h * 64 + kt * 32 + quad * 8;
    int c = n * 16 + l15;
    s8v v;
#pragma unroll
    for (int j = 0; j < 8; ++j) v[j] = (short)f2bf(Wproj[(size_t)(r0 + j) * 512 + c]);
    *(s8v*)&Wpfrag[(size_t)blk * 512 + lane * 8] = v;
}

// gkv[h*256 + s*64 + c]: s=0 g@Wk, 1 b@Wk, 2 g@Wv, 3 b@Wv. 32 blocks x 256 thr.
__global__ void gemv_g(const float* __restrict__ Wkv, const float* __restrict__ gamma,
                       const float* __restrict__ beta, float* __restrict__ gkv) {
    __shared__ float part[256];
    int blk = blockIdx.x; int h = blk >> 2, s = blk & 3;
    int c = threadIdx.x & 63, rc = threadIdx.x >> 6;
    int col = (s < 2) ? (h * 64 + c) : (512 + h * 64 + c);
    const float* vec = (s & 1) ? beta : gamma;
    float acc = 0.f;
    for (int r = rc * 128; r < rc * 128 + 128; ++r)
        acc += vec[r] * Wkv[(size_t)r * 1024 + col];
    part[threadIdx.x] = acc;
    __syncthreads();
    if (threadIdx.x < 64)
        gkv[h * 256 + s * 64 + c] = part[threadIdx.x] + part[threadIdx.x + 64]
                                  + part[threadIdx.x + 128] + part[threadIdx.x + 192];
}

// LDS map (bytes), all matrices XOR-swizzled (group g = col>>3, g' = g ^ (row & M)):
//  XS   @ 0      65536  [64][512] bf16, M=7   raw x rows (4 batches x 16)
//  PS2  @ 65536  49152  [48][512] bf16, M=7   raw pooled rows (4 x 12)
//  QH   @ 114688  8192  [64][64]  bf16, M=7   q(h) then O(h) overlay
//  KH   @ 122880 16384  [4][32][64] bf16, M=7 (by key)
//  VT   @ 139264 16384  [4][64][32] bf16, M=3 (by d)   v transposed
//  PB   @ 155648  4096  [4][16][32] bf16, M=3 (by row) softmax P
//  SRAW @ 159744   512  [64][2] f32 (mu, E[x^2])
//  SX   @ 160256   192  [48] f32 cross-dots
//  SFIN @ 160448  1024  [4][32][2] f32 (rstd, -rstd*mu); keys 28-31 = (0,0)
__global__ __launch_bounds__(1024) void fused_spa(
    const float* __restrict__ x,
    const u16*  __restrict__ Wfrag,
    const u16*  __restrict__ Wpfrag,
    const float* __restrict__ gkv,
    const float* __restrict__ bproj,
    float* __restrict__ out)
{
    __shared__ __align__(16) unsigned char smem[161472];
    u16*   XS   = (u16*)(smem);
    u16*   PS2  = (u16*)(smem + 65536);
    u16*   QH   = (u16*)(smem + 114688);
    u16*   KH   = (u16*)(smem + 122880);
    u16*   VT   = (u16*)(smem + 139264);
    u16*   PB   = (u16*)(smem + 155648);
    float* SRAW = (float*)(smem + 159744);
    float* SX   = (float*)(smem + 160256);
    float* SFIN = (float*)(smem + 160448);

    const int tid  = (int)threadIdx.x;
    const int w    = tid >> 6;
    const int lane = tid & 63;
    const int l15  = lane & 15;
    const int quad = lane >> 4;
    const int xr7  = l15 & 7;
    const size_t grow0 = (size_t)blockIdx.x * 64;

    // ---- S1: stage x (f32) -> XS bf16 swizzled
    {
        int row = tid >> 4;
        int gbase = (tid & 15) * 4;
        const float4* src = (const float4*)(x + (grow0 + row) * 512 + gbase * 8);
        int rx = row & 7;
#pragma unroll
        for (int i = 0; i < 4; ++i) {
            float4 f0 = src[2 * i], f1 = src[2 * i + 1];
            s8v o;
            o[0] = (short)f2bf(f0.x); o[1] = (short)f2bf(f0.y);
            o[2] = (short)f2bf(f0.z); o[3] = (short)f2bf(f0.w);
            o[4] = (short)f2bf(f1.x); o[5] = (short)f2bf(f1.y);
            o[6] = (short)f2bf(f1.z); o[7] = (short)f2bf(f1.w);
            *(s8v*)&XS[row * 512 + (((gbase + i) ^ rx) << 3)] = o;
        }
    }
    __syncthreads();

    // ---- S2a: per-row stats, cross dots, PS2 build
    {
#pragma unroll
        for (int i = 0; i < 4; ++i) {
            int row = w * 4 + i;
            s8v t = *(const s8v*)&XS[row * 512 + ((lane ^ (row & 7)) << 3)];
            float s = 0.f, s2 = 0.f;
#pragma unroll
            for (int j = 0; j < 8; ++j) { float v = bf2f((u16)t[j]); s += v; s2 += v * v; }
#pragma unroll
            for (int d = 1; d < 64; d <<= 1) { s += __shfl_xor(s, d); s2 += __shfl_xor(s2, d); }
            if (lane == 0) { SRAW[row * 2] = s * (1.f/512.f); SRAW[row * 2 + 1] = s2 * (1.f/512.f); }
        }
#pragma unroll
        for (int i = 0; i < 3; ++i) {
            int d = w * 3 + i;
            int b = d / 12, j = d % 12;
            int ra = b * 16 + POOL_A[j], rb = b * 16 + POOL_B[j];
            s8v ta = *(const s8v*)&XS[ra * 512 + ((lane ^ (ra & 7)) << 3)];
            s8v tb = *(const s8v*)&XS[rb * 512 + ((lane ^ (rb & 7)) << 3)];
            float s = 0.f;
#pragma unroll
            for (int j8 = 0; j8 < 8; ++j8) s += bf2f((u16)ta[j8]) * bf2f((u16)tb[j8]);
#pragma unroll
            for (int dd = 1; dd < 64; dd <<= 1) s += __shfl_xor(s, dd);
            if (lane == 0) SX[d] = s * (1.f/512.f);
        }
        if (tid < 768) {
            int row = tid >> 4;                 // 0..47
            int b = row / 12, j = row % 12;
            int ra = b * 16 + POOL_A[j], rb = b * 16 + POOL_B[j];
            int gbase = (tid & 15) * 4;
            int rx = row & 7, rax = ra & 7, rbx = rb & 7;
#pragma unroll
            for (int i = 0; i < 4; ++i) {
                int g = gbase + i;
                s8v ta = *(const s8v*)&XS[ra * 512 + ((g ^ rax) << 3)];
                s8v tb = *(const s8v*)&XS[rb * 512 + ((g ^ rbx) << 3)];
                s8v o;
#pragma unroll
                for (int j8 = 0; j8 < 8; ++j8)
                    o[j8] = (short)f2bf(0.5f * (bf2f((u16)ta[j8]) + bf2f((u16)tb[j8])));
                *(s8v*)&PS2[row * 512 + ((g ^ rx) << 3)] = o;
            }
        }
    }
    __syncthreads();

    // ---- S2b: finalize (rstd, -rstd*mu) per (batch, key)
    if (tid < 128) {
        int b = tid >> 5, key = tid & 31;
        float rstd = 0.f, nmu = 0.f;
        if (key < 16) {
            float mu = SRAW[(b * 16 + key) * 2], E2 = SRAW[(b * 16 + key) * 2 + 1];
            rstd = rsqrtf(E2 - mu * mu + 1e-5f);
            nmu = -rstd * mu;
        } else if (key < 28) {
            int j = key - 16;
            int ra = b * 16 + POOL_A[j], rb = b * 16 + POOL_B[j];
            float ma = SRAW[ra * 2], mb = SRAW[rb * 2];
            float Ea = SRAW[ra * 2 + 1], Eb = SRAW[rb * 2 + 1];
            float mu = 0.5f * (ma + mb);
            float E2 = 0.25f * (Ea + 2.f * SX[b * 12 + j] + Eb);
            rstd = rsqrtf(E2 - mu * mu + 1e-5f);
            nmu = -rstd * mu;
        }
        SFIN[(b * 32 + key) * 2] = rstd;
        SFIN[(b * 32 + key) * 2 + 1] = nmu;
    }
    __syncthreads();

    f4v psum[4][4] = {};   // proj accumulators (waves 8-15): [t][m]

    for (int h = 0; h < 8; ++h) {
        // ---- P1: qkv GEMM. w0: q; w1/w2: k (keys 0-15 / 16-31); w3/w4: v.
        if (w < 5) {
            int ntbase = (w == 0) ? 0 : (w <= 2 ? 4 : 8);
            bool hi = (w == 2 || w == 4);       // PS2 half (keys 16-31)
            f4v acc[4][4] = {};                 // [nt][m]
            for (int kt = 0; kt < 16; ++kt) {
                s8v A[4];
#pragma unroll
                for (int m = 0; m < 4; ++m) {
                    int row = hi ? (m * 12 + l15) : (m * 16 + l15);
                    const u16* Ab = hi ? PS2 : XS;
                    A[m] = *(const s8v*)&Ab[row * 512 + (((kt * 4 + quad) ^ (row & 7)) << 3)];
                }
#pragma unroll
                for (int nt = 0; nt < 4; ++nt) {
                    s8v B = *(const s8v*)&Wfrag[((size_t)((h * 12 + ntbase + nt) * 16 + kt)) * 512 + lane * 8];
#pragma unroll
                    for (int m = 0; m < 4; ++m) acc[nt][m] = mfma16(A[m], B, acc[nt][m]);
                }
            }
            if (w == 0) {                       // q epilogue (x 1/8)
#pragma unroll
                for (int nt = 0; nt < 4; ++nt)
#pragma unroll
                    for (int m = 0; m < 4; ++m)
#pragma unroll
                        for (int r = 0; r < 4; ++r) {
                            int row = m * 16 + quad * 4 + r;
                            QH[row * 64 + ((((nt * 2 + (l15 >> 3)) ^ (row & 7)) << 3)) + (l15 & 7)]
                                = f2bf(acc[nt][m][r] * 0.125f);
                        }
            } else if (w <= 2) {                // k epilogue -> KH
                int kbase = hi ? 16 : 0;
                float gk[4], bk[4];
#pragma unroll
                for (int nt = 0; nt < 4; ++nt) {
                    int d = nt * 16 + l15;
                    gk[nt] = gkv[h * 256 + d];
                    bk[nt] = gkv[h * 256 + 64 + d];
                }
#pragma unroll
                for (int m = 0; m < 4; ++m)
#pragma unroll
                    for (int r = 0; r < 4; ++r) {
                        int key = kbase + quad * 4 + r;
                        float rstd = SFIN[(m * 32 + key) * 2];
                        float nmu  = SFIN[(m * 32 + key) * 2 + 1];
#pragma unroll
                        for (int nt = 0; nt < 4; ++nt) {
                            float val = rstd * acc[nt][m][r] + nmu * gk[nt] + bk[nt];
                            KH[(m * 32 + key) * 64 + (((nt * 2 + (l15 >> 3)) ^ (key & 7)) << 3) + (l15 & 7)]
                                = f2bf(val);
                        }
                    }
            } else {                            // v epilogue -> VT (zero dead keys)
                int kbase = hi ? 16 : 0;
                float gv[4], bv[4];
#pragma unroll
                for (int nt = 0; nt < 4; ++nt) {
                    int d = nt * 16 + l15;
                    gv[nt] = gkv[h * 256 + 128 + d];
                    bv[nt] = gkv[h * 256 + 192 + d];
                }
#pragma unroll
                for (int m = 0; m < 4; ++m)
#pragma unroll
                    for (int r = 0; r < 4; ++r) {
                        int key = kbase + quad * 4 + r;
                        float rstd = SFIN[(m * 32 + key) * 2];
                        float nmu  = SFIN[(m * 32 + key) * 2 + 1];
#pragma unroll
                        for (int nt = 0; nt < 4; ++nt) {
                            float val = rstd * acc[nt][m][r] + nmu * gv[nt] + bv[nt];
                            if (key >= 28) val = 0.f;
                            int d = nt * 16 + l15;
                            VT[(m * 64 + d) * 32 + ((((key >> 3) ^ (d & 3)) << 3)) + (key & 7)]
                                = f2bf(val);
                        }
                    }
            }
        }
        __syncthreads();

        // ---- P2: attention, wave w = batch (w < 4)
        if (w < 4) {
            int b = w;
            f4v s0 = {}, s1 = {};
#pragma unroll
            for (int kt = 0; kt < 2; ++kt) {
                int g = kt * 4 + quad;
                s8v aq = *(const s8v*)&QH[(b * 16 + l15) * 64 + ((g ^ xr7) << 3)];
                s8v b0 = *(const s8v*)&KH[(b * 32 + l15) * 64 + ((g ^ xr7) << 3)];
                s8v b1 = *(const s8v*)&KH[(b * 32 + 16 + l15) * 64 + ((g ^ xr7) << 3)];
                s0 = mfma16(aq, b0, s0);
                s1 = mfma16(aq, b1, s1);
            }
            bool valid1 = (l15 < 12);
#pragma unroll
            for (int r = 0; r < 4; ++r) {
                float v0 = s0[r];
                float v1 = valid1 ? s1[r] : -1e30f;
                float mx = fmaxf(v0, v1);
#pragma unroll
                for (int d = 1; d < 16; d <<= 1) mx = fmaxf(mx, __shfl_xor(mx, d));
                float p0 = __expf(v0 - mx);
                float p1 = valid1 ? __expf(v1 - mx) : 0.f;
                float sm = p0 + p1;
#pragma unroll
                for (int d = 1; d < 16; d <<= 1) sm += __shfl_xor(sm, d);
                float inv = 1.f / sm;
                int row = quad * 4 + r;
                PB[(b * 16 + row) * 32 + ((((l15 >> 3)) ^ (row & 3)) << 3) + (l15 & 7)]
                    = f2bf(p0 * inv);
                PB[(b * 16 + row) * 32 + (((2 + (l15 >> 3)) ^ (row & 3)) << 3) + (l15 & 7)]
                    = f2bf(p1 * inv);
            }
            // PV -> O into QH overlay
            s8v ap = *(const s8v*)&PB[(b * 16 + l15) * 32 + (((quad ^ (l15 & 3))) << 3)];
            f4v z = {0.f, 0.f, 0.f, 0.f};
#pragma unroll
            for (int nt = 0; nt < 4; ++nt) {
                s8v bv = *(const s8v*)&VT[(b * 64 + nt * 16 + l15) * 32 + ((quad ^ (l15 & 3)) << 3)];
                f4v o = mfma16(ap, bv, z);
#pragma unroll
                for (int r = 0; r < 4; ++r) {
                    int row = b * 16 + quad * 4 + r;
                    QH[row * 64 + (((nt * 2 + (l15 >> 3)) ^ (row & 7)) << 3) + (l15 & 7)]
                        = f2bf(o[r]);
                }
            }
        }
        __syncthreads();

        // ---- P3: proj accumulation, waves 8-15, n-tiles (w-8)*4 .. +3
        if (w >= 8) {
            int nb = (w - 8) * 4;
#pragma unroll
            for (int kt = 0; kt < 2; ++kt) {
                s8v A[4];
#pragma unroll
                for (int m = 0; m < 4; ++m) {
                    int row = m * 16 + l15;
                    A[m] = *(const s8v*)&QH[row * 64 + (((kt * 4 + quad) ^ (row & 7)) << 3)];
                }
#pragma unroll
                for (int t = 0; t < 4; ++t) {
                    s8v B = *(const s8v*)&Wpfrag[((size_t)((h * 2 + kt) * 32 + nb + t)) * 512 + lane * 8];
#pragma unroll
                    for (int m = 0; m < 4; ++m) psum[t][m] = mfma16(A[m], B, psum[t][m]);
                }
            }
        }
        __syncthreads();
    }

    // ---- final: out = psum + bias (f32)
    if (w >= 8) {
        int nb = (w - 8) * 4;
#pragma unroll
        for (int t = 0; t < 4; ++t) {
            int n0 = (nb + t) * 16;
            float bias = bproj[n0 + l15];
#pragma unroll
            for (int m = 0; m < 4; ++m)
#pragma unroll
                for (int r = 0; r < 4; ++r)
                    out[(grow0 + m * 16 + quad * 4 + r) * 512 + n0 + l15]
                        = psum[t][m][r] + bias;
        }
    }
}

extern "C" void kernel_launch(void* const* d_in, const int* in_sizes, int n_in,
                              void* d_out, int out_size, void* d_ws, size_t ws_size,
                              hipStream_t stream) {
    const float* x     = (const float*)d_in[0];
    const float* Wq    = (const float*)d_in[1];
    const float* Wkv   = (const float*)d_in[2];
    const float* Wproj = (const float*)d_in[3];
    const float* bproj = (const float*)d_in[4];
    const float* gamma = (const float*)d_in[5];
    const float* beta  = (const float*)d_in[6];
    float* out = (float*)d_out;

    u16*   Wfrag  = (u16*)d_ws;                            // 1536*512 u16 = 1.5 MiB
    u16*   Wpfrag = Wfrag + (size_t)1536 * 512;            // 512*512 u16 = 0.5 MiB
    float* gkv    = (float*)(Wpfrag + (size_t)512 * 512);  // 2048 f32

    pack_wcat<<<1536, 64, 0, stream>>>(Wq, Wkv, gamma, Wfrag);
    pack_wp<<<512, 64, 0, stream>>>(Wproj, Wpfrag);
    gemv_g<<<32, 256, 0, stream>>>(Wkv, gamma, beta, gkv);

    fused_spa<<<1024, 1024, 0, stream>>>(x, Wfrag, Wpfrag, gkv, bproj, out);
}